// Round 6
// baseline (735.425 us; speedup 1.0000x reference)
//
#include <hip/hip_runtime.h>
#include <hip/hip_bf16.h>

// SACRSN_v84 — v6: OUTPUT IS FLOAT32 (established by R5 probe).
// One wave per row, deterministic serial reductions, exact f64 VQ argmin.
// Outputs (f32, concatenated): combined[8192][4736], vq_loss[8192],
// indices[8192] (as float), slot_entropy, norm_entropy.

#define RSTRIDE 4736
static constexpr size_t OFF_VQLOSS = 38797312UL;  // 8192*4736
static constexpr size_t OFF_IDX    = 38805504UL;
static constexpr size_t OFF_SENT   = 38813696UL;
static constexpr size_t OFF_NENT   = 38813697UL;

struct Params {
  const float* curr_r; const float* curr_i;
  const float* mem_r;  const float* mem_i;
  const float* codebook;
  const float* qkv_Wr; const float* qkv_Wi; const float* qkv_br; const float* qkv_bi;
  const float* quad_Wr; const float* quad_Wi; const float* quad_br; const float* quad_bi;
  const float* sens_Wr; const float* sens_Wi; const float* sens_br; const float* sens_bi;
  const float* vis_pal; const float* aud_pal;
  const float* gate_W; const float* gate_b;
  const float* addr_W; const float* addr_b;
  const float* ln_gr; const float* ln_br; const float* ln_gi; const float* ln_bi;
  float* out;
  int* hist;          // ws: 128 ints
  float* rowent;      // ws + 512 B: 8192 floats
};

__global__ __launch_bounds__(64) void row_kernel(Params P) {
  const int b = blockIdx.x;       // row 0..8191
  const int l = threadIdx.x;      // lane 0..63

  __shared__ float zr[64], zi[64];
  __shared__ float mR[32][65], mI[32][65];       // padded; later overwritten by tanh(nm)
  __shared__ double dist[128];
  __shared__ float s_qr[64], s_qi[64], s_kr[64], s_ki[64], s_vr[64], s_vi[64];
  __shared__ float sfl[128];
  __shared__ float tvq[64], tga[64], twg[64];
  __shared__ float alg[32], aww[32];
  __shared__ float simv[32], att[32];
  __shared__ float vsc[32], pvp[32], asc[32], pap[32];
  __shared__ float mnR[32], ivR[32], mnI[32], ivI[32];
  __shared__ float eff_[32];
  __shared__ int   stop3[3];
  __shared__ int   s_vidx;
  __shared__ float scal[8];

  float* orow = P.out + (size_t)b * RSTRIDE;

  // ---- stage row: z and mem ----
  {
    const size_t rz = (size_t)b * 64;
    zr[l] = P.curr_r[rz + l];
    zi[l] = P.curr_i[rz + l];
    const size_t mb = (size_t)b * 2048;
    for (int i = l; i < 2048; i += 64) {
      mR[i >> 6][i & 63] = P.mem_r[mb + i];
      mI[i >> 6][i & 63] = P.mem_i[mb + i];
    }
  }
  __syncthreads();

  // ---- VQ: exact squared distances (f64), 2 codes per lane ----
  for (int cc = 0; cc < 2; ++cc) {
    const int c = l + cc * 64;
    const float* cb = P.codebook + (size_t)c * 128;
    double a = 0.0;
    for (int x = 0; x < 64; ++x) { double d1 = (double)cb[x]      - (double)zr[x]; a = fma(d1, d1, a); }
    for (int x = 0; x < 64; ++x) { double d1 = (double)cb[64 + x] - (double)zi[x]; a = fma(d1, d1, a); }
    dist[c] = a;
  }
  __syncthreads();
  if (l == 0) {
    double best = dist[0]; int bi = 0;
    for (int c = 1; c < 128; ++c) if (dist[c] < best) { best = dist[c]; bi = c; }
    s_vidx = bi;
    atomicAdd(&P.hist[bi], 1);
  }
  __syncthreads();
  const int vidx = s_vidx;

  // ---- vq_loss + vq_r/vq_i writes ----
  {
    const float* cb = P.codebook + (size_t)vidx * 128;
    const float cr = cb[l], ci = cb[64 + l];
    const float d0 = cr - zr[l], d1 = ci - zi[l];
    tvq[l] = d0 * d0 + d1 * d1;
    orow[l]      = zr[l] + (cr - zr[l]);   // straight-through
    orow[64 + l] = zi[l] + (ci - zi[l]);
  }
  __syncthreads();
  if (l == 0) {
    float s = 0.f;
    for (int x = 0; x < 64; ++x) s += tvq[x];
    P.out[OFF_VQLOSS + b] = 0.25f * s * (1.0f / 128.0f);
    P.out[OFF_IDX + b]    = (float)vidx;
  }

  // ---- five complex linears (lane = output dim j) ----
  {
    const int j = l;
    for (int cl = 0; cl < 5; ++cl) {
      const float *Wr, *Wi, *br_, *bi_;
      if      (cl == 0) { Wr = P.qkv_Wr;        Wi = P.qkv_Wi;        br_ = P.qkv_br;       bi_ = P.qkv_bi;       }
      else if (cl == 1) { Wr = P.qkv_Wr + 4096; Wi = P.qkv_Wi + 4096; br_ = P.qkv_br + 64;  bi_ = P.qkv_bi + 64;  }
      else if (cl == 2) { Wr = P.qkv_Wr + 8192; Wi = P.qkv_Wi + 8192; br_ = P.qkv_br + 128; bi_ = P.qkv_bi + 128; }
      else if (cl == 3) { Wr = P.quad_Wr;       Wi = P.quad_Wi;       br_ = P.quad_br;      bi_ = P.quad_bi;      }
      else              { Wr = P.sens_Wr;       Wi = P.sens_Wi;       br_ = P.sens_br;      bi_ = P.sens_bi;      }
      float aRR = 0.f, aRI = 0.f, aIR = 0.f, aII = 0.f;
      for (int d = 0; d < 64; ++d) {
        const float wr = Wr[d * 64 + j], wi = Wi[d * 64 + j];
        const float xr = zr[d], xi = zi[d];
        aRR += xr * wr; aRI += xr * wi; aIR += xi * wr; aII += xi * wi;
      }
      const float oR = (aRR + br_[j]) - (aII + bi_[j]);
      const float oI = (aRI + bi_[j]) + (aIR + br_[j]);
      if      (cl == 0) { s_qr[j] = oR; s_qi[j] = oI; }
      else if (cl == 1) { s_kr[j] = oR; s_ki[j] = oI; }
      else if (cl == 2) { s_vr[j] = oR; s_vi[j] = oI; }
      else if (cl == 3) { orow[512 + j] = -oI;    // q_r = -zi
                          orow[576 + j] = oR; }   // q_i =  zr
      else              { sfl[j] = oR; sfl[64 + j] = oI; }
    }
  }
  __syncthreads();

  // ---- gate + write_gate partials ----
  tga[l] = s_qr[l] * s_kr[l] + s_qi[l] * s_ki[l];
  twg[l] = zr[l] * P.gate_W[l] + zi[l] * P.gate_W[64 + l];
  __syncthreads();
  if (l == 0) {
    float g = 0.f, wg = 0.f;
    for (int x = 0; x < 64; ++x) { g += tga[x]; wg += twg[x]; }
    scal[0] = 1.f / (1.f + expf(-g));
    scal[1] = 1.f / (1.f + expf(-(wg + P.gate_b[0])));
  }
  __syncthreads();
  orow[128 + l] = s_vr[l] * scal[0];   // g_r
  orow[192 + l] = s_vi[l] * scal[0];   // g_i

  // ---- addr logits / softmax / entropy / top-3 / eff ----
  if (l < 32) {
    float a = P.addr_b[l];
    for (int d = 0; d < 64; ++d) a += zr[d] * P.addr_W[d * 32 + l];
    for (int d = 0; d < 64; ++d) a += zi[d] * P.addr_W[(64 + d) * 32 + l];
    alg[l] = a;
  }
  __syncthreads();
  if (l == 0) {
    float mx = alg[0];
    for (int x = 1; x < 32; ++x) mx = fmaxf(mx, alg[x]);
    scal[2] = mx;
  }
  __syncthreads();
  if (l < 32) aww[l] = expf(alg[l] - scal[2]);
  __syncthreads();
  if (l == 0) {
    float sm = 0.f;
    for (int x = 0; x < 32; ++x) sm += aww[x];
    scal[3] = sm;
  }
  __syncthreads();
  if (l < 32) aww[l] = aww[l] / scal[3];
  __syncthreads();
  if (l == 0) {
    float es = 0.f;
    for (int x = 0; x < 32; ++x) es += -(aww[x] * logf(aww[x] + 1e-10f));
    P.rowent[b] = es;
    float wc[32];
    for (int x = 0; x < 32; ++x) wc[x] = aww[x];
    float sumtop = 0.f;
    for (int p = 0; p < 3; ++p) {
      float bv = wc[0]; int bi2 = 0;
      for (int x = 1; x < 32; ++x) if (wc[x] > bv) { bv = wc[x]; bi2 = x; }  // ties -> lower idx
      stop3[p] = bi2; sumtop += bv; wc[bi2] = -1e30f;
    }
    scal[4] = sumtop;
  }
  __syncthreads();
  if (l < 32) {
    const bool pick = (l == stop3[0]) | (l == stop3[1]) | (l == stop3[2]);
    eff_[l] = pick ? scal[1] * aww[l] / (scal[4] + 1e-6f) : 0.f;
  }

  // ---- memory attention: sim, softmax, read ----
  if (l < 32) {
    float s1 = 0.f;
    for (int d = 0; d < 64; ++d) s1 += mR[l][d] * zr[d] + mI[l][d] * zi[d];
    simv[l] = s1;
  }
  __syncthreads();
  if (l == 0) {
    float mx = simv[0];
    for (int x = 1; x < 32; ++x) mx = fmaxf(mx, simv[x]);
    scal[2] = mx;
  }
  __syncthreads();
  if (l < 32) att[l] = expf(simv[l] - scal[2]);
  __syncthreads();
  if (l == 0) {
    float sm = 0.f;
    for (int x = 0; x < 32; ++x) sm += att[x];
    scal[3] = sm;
  }
  __syncthreads();
  if (l < 32) att[l] = att[l] / scal[3];
  __syncthreads();
  {
    float ar = 0.f, ai = 0.f;
    for (int s = 0; s < 32; ++s) { ar += att[s] * mR[s][l]; ai += att[s] * mI[s][l]; }
    orow[256 + l] = ar;
    orow[320 + l] = ai;
  }
  __syncthreads();   // all reads of mR/mI done before in-place overwrite

  // ---- nm = tanh(mem + eff*(z - mem)), then layernorm ----
  for (int s = 0; s < 32; ++s) {
    const float e = eff_[s];
    mR[s][l] = tanhf(mR[s][l] + e * (zr[l] - mR[s][l]));
    mI[s][l] = tanhf(mI[s][l] + e * (zi[l] - mI[s][l]));
  }
  __syncthreads();
  if (l < 32) {
    float s1 = 0.f;
    for (int d = 0; d < 64; ++d) s1 += mR[l][d];
    const float mn = s1 * (1.f / 64.f);
    float s2 = 0.f;
    for (int d = 0; d < 64; ++d) { const float dd = mR[l][d] - mn; s2 += dd * dd; }
    mnR[l] = mn; ivR[l] = 1.f / sqrtf(s2 * (1.f / 64.f) + 1e-6f);
  } else {
    const int s = l - 32;
    float s1 = 0.f;
    for (int d = 0; d < 64; ++d) s1 += mI[s][d];
    const float mn = s1 * (1.f / 64.f);
    float s2 = 0.f;
    for (int d = 0; d < 64; ++d) { const float dd = mI[s][d] - mn; s2 += dd * dd; }
    mnI[s] = mn; ivI[s] = 1.f / sqrtf(s2 * (1.f / 64.f) + 1e-6f);
  }
  __syncthreads();
  {
    const float gR = P.ln_gr[l], bR = P.ln_br[l], gI = P.ln_gi[l], bI = P.ln_bi[l];
    for (int s = 0; s < 32; ++s) {
      orow[640  + s * 64 + l] = (mR[s][l] - mnR[s]) * ivR[s] * gR + bR;
      orow[2688 + s * 64 + l] = (mI[s][l] - mnI[s]) * ivI[s] * gI + bI;
    }
  }

  // ---- palette attends ----
  if (l < 32) {
    float sc = 0.f;
    const float* p = P.vis_pal + (size_t)l * 128;
    for (int x = 0; x < 128; ++x) sc += sfl[x] * p[x];
    vsc[l] = sc;
    float sa = 0.f;
    const float* q = P.aud_pal + (size_t)l * 128;
    for (int x = 0; x < 128; ++x) sa += sfl[x] * q[x];
    asc[l] = sa;
  }
  __syncthreads();
  if (l == 0) {
    float mx = vsc[0];
    for (int x = 1; x < 32; ++x) mx = fmaxf(mx, vsc[x]);
    scal[2] = mx;
    float ma = asc[0];
    for (int x = 1; x < 32; ++x) ma = fmaxf(ma, asc[x]);
    scal[5] = ma;
  }
  __syncthreads();
  if (l < 32) { pvp[l] = expf(vsc[l] - scal[2]); pap[l] = expf(asc[l] - scal[5]); }
  __syncthreads();
  if (l == 0) {
    float sv = 0.f, sa = 0.f;
    for (int x = 0; x < 32; ++x) { sv += pvp[x]; sa += pap[x]; }
    scal[3] = sv; scal[6] = sa;
  }
  __syncthreads();
  if (l < 32) { pvp[l] = pvp[l] / scal[3]; pap[l] = pap[l] / scal[6]; }
  __syncthreads();
  {
    float vr0 = 0.f, vi0 = 0.f, ar0 = 0.f, ai0 = 0.f;
    for (int a = 0; a < 32; ++a) {
      vr0 += pvp[a] * P.vis_pal[a * 128 + l];
      vi0 += pvp[a] * P.vis_pal[a * 128 + 64 + l];
      ar0 += pap[a] * P.aud_pal[a * 128 + l];
      ai0 += pap[a] * P.aud_pal[a * 128 + 64 + l];
    }
    orow[384 + l] = vr0 - ai0;   // exp_r = vis[:D] - aud[D:]
    orow[448 + l] = vi0 + ar0;   // exp_i = vis[D:] + aud[:D]
  }
}

__global__ __launch_bounds__(256) void finalize_k(const int* hist, const float* rowent,
                                                  float* out) {
  const int t = threadIdx.x;
  __shared__ float red[256];
  float se = 0.f;
  for (int i = t; i < 8192; i += 256) se += rowent[i];
  red[t] = se;
  __syncthreads();
  for (int off = 128; off >= 1; off >>= 1) {
    if (t < off) red[t] += red[t + off];
    __syncthreads();
  }
  if (t == 0) out[OFF_SENT] = red[0] / 8192.0f;
  __syncthreads();
  float ne = 0.f;
  if (t < 128) {
    const float pp = (float)hist[t] / 8192.0f;
    ne = -(pp * logf(pp + 1e-10f));
  }
  red[t] = ne;
  __syncthreads();
  for (int off = 128; off >= 1; off >>= 1) {
    if (t < off) red[t] += red[t + off];
    __syncthreads();
  }
  if (t == 0) out[OFF_NENT] = red[0] / logf(128.0f);
}

extern "C" void kernel_launch(void* const* d_in, const int* in_sizes, int n_in,
                              void* d_out, int out_size, void* d_ws, size_t ws_size,
                              hipStream_t stream) {
  (void)in_sizes; (void)n_in; (void)out_size; (void)ws_size;
  Params P;
  P.curr_r   = (const float*)d_in[0];
  P.curr_i   = (const float*)d_in[1];
  P.mem_r    = (const float*)d_in[2];
  P.mem_i    = (const float*)d_in[3];
  P.codebook = (const float*)d_in[4];
  P.qkv_Wr   = (const float*)d_in[5];
  P.qkv_Wi   = (const float*)d_in[6];
  P.qkv_br   = (const float*)d_in[7];
  P.qkv_bi   = (const float*)d_in[8];
  P.quad_Wr  = (const float*)d_in[9];
  P.quad_Wi  = (const float*)d_in[10];
  P.quad_br  = (const float*)d_in[11];
  P.quad_bi  = (const float*)d_in[12];
  P.sens_Wr  = (const float*)d_in[13];
  P.sens_Wi  = (const float*)d_in[14];
  P.sens_br  = (const float*)d_in[15];
  P.sens_bi  = (const float*)d_in[16];
  P.vis_pal  = (const float*)d_in[17];
  P.aud_pal  = (const float*)d_in[18];
  P.gate_W   = (const float*)d_in[19];
  P.gate_b   = (const float*)d_in[20];
  P.addr_W   = (const float*)d_in[21];
  P.addr_b   = (const float*)d_in[22];
  P.ln_gr    = (const float*)d_in[23];
  P.ln_br    = (const float*)d_in[24];
  P.ln_gi    = (const float*)d_in[25];
  P.ln_bi    = (const float*)d_in[26];
  P.out = (float*)d_out;
  P.hist = (int*)d_ws;
  P.rowent = (float*)((char*)d_ws + 512);

  hipMemsetAsync(d_ws, 0, 512, stream);
  row_kernel<<<dim3(8192), dim3(64), 0, stream>>>(P);
  finalize_k<<<dim3(1), dim3(256), 0, stream>>>(P.hist, P.rowent, (float*)d_out);
}

// Round 7
// 384.272 us; speedup vs baseline: 1.9138x; 1.9138x over previous
//
#include <hip/hip_runtime.h>
#include <hip/hip_bf16.h>

// SACRSN_v84 — v7: f32 output (confirmed R6), back to 256-thread / 8-rows-per-block
// wave-parallel structure (R1) for performance. Exact f64 VQ argmin preserved.

#define NROWS 8
#define NBLOCKS 1024          // 8192 / NROWS
#define RSTRIDE 4736          // combined row stride (10*64 + 2*2048)

static constexpr size_t OFF_VQLOSS = 38797312UL;  // 8192*4736
static constexpr size_t OFF_IDX    = 38805504UL;
static constexpr size_t OFF_SENT   = 38813696UL;
static constexpr size_t OFF_NENT   = 38813697UL;

struct Params {
  const float* curr_r; const float* curr_i;
  const float* mem_r;  const float* mem_i;
  const float* codebook;
  const float* qkv_Wr; const float* qkv_Wi; const float* qkv_br; const float* qkv_bi;
  const float* quad_Wr; const float* quad_Wi; const float* quad_br; const float* quad_bi;
  const float* sens_Wr; const float* sens_Wi; const float* sens_br; const float* sens_bi;
  const float* vis_pal; const float* aud_pal;
  const float* gate_W; const float* gate_b;
  const float* addr_W; const float* addr_b;
  const float* ln_gr; const float* ln_br; const float* ln_gi; const float* ln_bi;
  float* out;
  int* hist;          // ws: 128 ints
  float* slot_part;   // ws + 512 B: NBLOCKS floats
};

union __align__(16) ScratchU {
  struct { double cbn[128]; double redd[256]; } vq;               // 3 KB
  float w[64][64];                                                // 16 KB staged weights
  struct { float vis[NROWS][128]; float palp[NROWS][32]; } pal;   // 5 KB
};

__global__ __launch_bounds__(256) void fused_main(Params P) {
  const int t = threadIdx.x;
  const int bid = blockIdx.x;
  const int lane = t & 63;
  const int wv = t >> 6;

  __shared__ __align__(16) float s_zr[NROWS][64], s_zi[NROWS][64];
  __shared__ ScratchU u;
  __shared__ float s_qr[NROWS][64], s_qi[NROWS][64];
  __shared__ float s_kr[NROWS][64], s_ki[NROWS][64];
  __shared__ float s_vr[NROWS][64], s_vi[NROWS][64];
  __shared__ __align__(16) float s_sf[NROWS][128];
  __shared__ float s_eff[NROWS][32];
  __shared__ float s_sim[32], s_attn[32];
  __shared__ float s_rr[4][8][8], s_ri[4][8][8];
  __shared__ float s_gate[NROWS], s_rowent[NROWS], s_vqls[NROWS];
  __shared__ int s_idx[NROWS];
  __shared__ double s_cv[2];
  __shared__ int s_ci[2];

  // ---------------- P0: stage curr (z) into LDS ----------------
  {
    const float* cr = P.curr_r + (size_t)bid * (NROWS * 64);
    const float* ci = P.curr_i + (size_t)bid * (NROWS * 64);
    float* zr = &s_zr[0][0];
    float* zi = &s_zi[0][0];
    for (int i = t; i < NROWS * 64; i += 256) { zr[i] = cr[i]; zi[i] = ci[i]; }
  }

  // ---------------- P0b: codebook squared norms (f64) ----------------
  {
    const int c = t & 127, h = t >> 7;
    const float* cb = P.codebook + c * 128 + h * 64;
    double a = 0.0;
    for (int d = 0; d < 64; ++d) { double w = (double)cb[d]; a = fma(w, w, a); }
    u.vq.redd[t] = a;
    __syncthreads();                       // also publishes s_zr/s_zi
    if (t < 128) u.vq.cbn[t] = u.vq.redd[t] + u.vq.redd[t + 128];
    __syncthreads();
  }

  // ---------------- P1: VQ argmin (f64, first-index tie-break) ----------------
  {
    const int c = t & 127, h = t >> 7;
    const float* cb = P.codebook + c * 128 + h * 64;
    const float (*zb)[64] = h ? s_zi : s_zr;
    double acc[NROWS];
    #pragma unroll
    for (int r = 0; r < NROWS; ++r) acc[r] = 0.0;
    for (int d = 0; d < 64; ++d) {
      const double w = (double)cb[d];
      #pragma unroll
      for (int r = 0; r < NROWS; ++r) acc[r] = fma(w, (double)zb[r][d], acc[r]);
    }
    #pragma unroll 1
    for (int r = 0; r < NROWS; ++r) {
      u.vq.redd[t] = acc[r];
      __syncthreads();
      if (t < 128) {
        double sv = u.vq.cbn[t] - 2.0 * (u.vq.redd[t] + u.vq.redd[t + 128]);
        int si = t;
        #pragma unroll
        for (int m = 1; m <= 32; m <<= 1) {
          double ov = __shfl_xor(sv, m);
          int oi = __shfl_xor(si, m);
          if (ov < sv || (ov == sv && oi < si)) { sv = ov; si = oi; }
        }
        if (lane == 0) { s_cv[t >> 6] = sv; s_ci[t >> 6] = si; }
      }
      __syncthreads();
      if (t == 0) {
        int win = (s_cv[1] < s_cv[0] || (s_cv[1] == s_cv[0] && s_ci[1] < s_ci[0]))
                  ? s_ci[1] : s_ci[0];
        s_idx[r] = win;
        atomicAdd(&P.hist[win], 1);
      }
      __syncthreads();
    }
  }

  // ---------------- P1b: vq_loss (wave-local, 2 rows per wave) ----------------
  {
    #pragma unroll
    for (int rr = 0; rr < 2; ++rr) {
      const int r = wv * 2 + rr;
      const float* cb = P.codebook + (size_t)s_idx[r] * 128;
      float d0_ = cb[lane] - s_zr[r][lane];
      float d1_ = cb[64 + lane] - s_zi[r][lane];
      float v = d0_ * d0_ + d1_ * d1_;
      #pragma unroll
      for (int m = 1; m <= 32; m <<= 1) v += __shfl_xor(v, m);
      if (lane == 0) s_vqls[r] = 0.25f * v * (1.0f / 128.0f);
    }
  }

  // ---------------- P2: five complex linears (q,k,v,quad,sens) ----------------
  {
    const int j = t & 63, rg = t >> 6;
    const float* Wr_tab[5] = {P.qkv_Wr, P.qkv_Wr + 4096, P.qkv_Wr + 8192, P.quad_Wr, P.sens_Wr};
    const float* Wi_tab[5] = {P.qkv_Wi, P.qkv_Wi + 4096, P.qkv_Wi + 8192, P.quad_Wi, P.sens_Wi};
    const float* br_tab[5] = {P.qkv_br, P.qkv_br + 64, P.qkv_br + 128, P.quad_br, P.sens_br};
    const float* bi_tab[5] = {P.qkv_bi, P.qkv_bi + 64, P.qkv_bi + 128, P.quad_bi, P.sens_bi};
    #pragma unroll 1
    for (int cl = 0; cl < 5; ++cl) {
      __syncthreads();   // previous user of u.* done
      { const float4* src = (const float4*)Wr_tab[cl];
        float4* dst = (float4*)&u.w[0][0];
        for (int i = t; i < 1024; i += 256) dst[i] = src[i]; }
      __syncthreads();
      float aRR0 = 0.f, aRR1 = 0.f, aIR0 = 0.f, aIR1 = 0.f;
      for (int d4 = 0; d4 < 64; d4 += 4) {
        float4 zr0 = *(const float4*)&s_zr[rg][d4];
        float4 zr1 = *(const float4*)&s_zr[rg + 4][d4];
        float4 zi0 = *(const float4*)&s_zi[rg][d4];
        float4 zi1 = *(const float4*)&s_zi[rg + 4][d4];
        float w0 = u.w[d4 + 0][j], w1 = u.w[d4 + 1][j];
        float w2 = u.w[d4 + 2][j], w3 = u.w[d4 + 3][j];
        aRR0 += zr0.x * w0 + zr0.y * w1 + zr0.z * w2 + zr0.w * w3;
        aRR1 += zr1.x * w0 + zr1.y * w1 + zr1.z * w2 + zr1.w * w3;
        aIR0 += zi0.x * w0 + zi0.y * w1 + zi0.z * w2 + zi0.w * w3;
        aIR1 += zi1.x * w0 + zi1.y * w1 + zi1.z * w2 + zi1.w * w3;
      }
      __syncthreads();
      { const float4* src = (const float4*)Wi_tab[cl];
        float4* dst = (float4*)&u.w[0][0];
        for (int i = t; i < 1024; i += 256) dst[i] = src[i]; }
      __syncthreads();
      float aRI0 = 0.f, aRI1 = 0.f, aII0 = 0.f, aII1 = 0.f;
      for (int d4 = 0; d4 < 64; d4 += 4) {
        float4 zr0 = *(const float4*)&s_zr[rg][d4];
        float4 zr1 = *(const float4*)&s_zr[rg + 4][d4];
        float4 zi0 = *(const float4*)&s_zi[rg][d4];
        float4 zi1 = *(const float4*)&s_zi[rg + 4][d4];
        float w0 = u.w[d4 + 0][j], w1 = u.w[d4 + 1][j];
        float w2 = u.w[d4 + 2][j], w3 = u.w[d4 + 3][j];
        aRI0 += zr0.x * w0 + zr0.y * w1 + zr0.z * w2 + zr0.w * w3;
        aRI1 += zr1.x * w0 + zr1.y * w1 + zr1.z * w2 + zr1.w * w3;
        aII0 += zi0.x * w0 + zi0.y * w1 + zi0.z * w2 + zi0.w * w3;
        aII1 += zi1.x * w0 + zi1.y * w1 + zi1.z * w2 + zi1.w * w3;
      }
      const float brj = br_tab[cl][j], bij = bi_tab[cl][j];
      #pragma unroll
      for (int hh = 0; hh < 2; ++hh) {
        const int r = rg + hh * 4;
        const float pRR = hh ? aRR1 : aRR0;
        const float pII = hh ? aII1 : aII0;
        const float pRI = hh ? aRI1 : aRI0;
        const float pIR = hh ? aIR1 : aIR0;
        const float oR = (pRR + brj) - (pII + bij);
        const float oI = (pRI + bij) + (pIR + brj);
        if (cl == 0)      { s_qr[r][j] = oR; s_qi[r][j] = oI; }
        else if (cl == 1) { s_kr[r][j] = oR; s_ki[r][j] = oI; }
        else if (cl == 2) { s_vr[r][j] = oR; s_vi[r][j] = oI; }
        else if (cl == 3) {  // quad: q_r = -zi, q_i = zr
          float* orow = P.out + ((size_t)bid * NROWS + r) * RSTRIDE;
          orow[512 + j] = -oI;
          orow[576 + j] = oR;
        } else            { s_sf[r][j] = oR; s_sf[r][64 + j] = oI; }
      }
    }
    __syncthreads();
  }

  // ---------------- P3: gate, write_gate, addr softmax/entropy/top-3 ----------------
  {
    const int r = t >> 5, l = t & 31;
    // gate = sigmoid(sum(qr*kr + qi*ki))
    float g = s_qr[r][l] * s_kr[r][l] + s_qi[r][l] * s_ki[r][l]
            + s_qr[r][l + 32] * s_kr[r][l + 32] + s_qi[r][l + 32] * s_ki[r][l + 32];
    #pragma unroll
    for (int m = 16; m >= 1; m >>= 1) g += __shfl_xor(g, m);
    if (l == 0) s_gate[r] = 1.f / (1.f + expf(-g));
    // write_gate = sigmoid(z @ gate_W + gate_b)
    float wg = 0.f;
    #pragma unroll
    for (int q4 = 0; q4 < 4; ++q4) {
      int jj = l + q4 * 32;
      float z = (jj < 64) ? s_zr[r][jj] : s_zi[r][jj - 64];
      wg += z * P.gate_W[jj];
    }
    #pragma unroll
    for (int m = 16; m >= 1; m >>= 1) wg += __shfl_xor(wg, m);
    const float wgate = 1.f / (1.f + expf(-(wg + P.gate_b[0])));
    // addr logits, softmax, entropy
    float lg = 0.f;
    for (int jj = 0; jj < 64; ++jj) lg += s_zr[r][jj] * P.addr_W[jj * 32 + l];
    for (int jj = 0; jj < 64; ++jj) lg += s_zi[r][jj] * P.addr_W[(64 + jj) * 32 + l];
    lg += P.addr_b[l];
    float mx = lg;
    #pragma unroll
    for (int m = 16; m >= 1; m >>= 1) mx = fmaxf(mx, __shfl_xor(mx, m));
    float e = expf(lg - mx);
    float sm = e;
    #pragma unroll
    for (int m = 16; m >= 1; m >>= 1) sm += __shfl_xor(sm, m);
    const float w = e / sm;
    float es = -(w * logf(w + 1e-10f));
    #pragma unroll
    for (int m = 16; m >= 1; m >>= 1) es += __shfl_xor(es, m);
    if (l == 0) s_rowent[r] = es;
    // top-3 (lax.top_k semantics: ties -> lower index)
    const float myw = w;
    bool picked = false;
    float val = w; int idx = l;
    float sumtop = 0.f;
    #pragma unroll
    for (int it = 0; it < 3; ++it) {
      float v2 = val; int i2 = idx;
      #pragma unroll
      for (int m = 16; m >= 1; m >>= 1) {
        float ov = __shfl_xor(v2, m); int oi = __shfl_xor(i2, m);
        if (ov > v2 || (ov == v2 && oi < i2)) { v2 = ov; i2 = oi; }
      }
      sumtop += v2;
      if (l == i2) { picked = true; val = -1e30f; }
    }
    s_eff[r][l] = picked ? wgate * (myw / (sumtop + 1e-6f)) : 0.f;
  }
  __syncthreads();

  // ---------------- P4: per-row memory attention + nm (tanh + layernorm) ----------------
  #pragma unroll 1
  for (int r = 0; r < NROWS; ++r) {
    const size_t bb = (size_t)bid * NROWS + r;
    const int s = t >> 3, k = t & 7, d0 = k * 8;
    const float* mrp = P.mem_r + ((bb * 32 + s) * 64 + d0);
    const float* mip = P.mem_i + ((bb * 32 + s) * 64 + d0);
    float4 a0 = *(const float4*)mrp, a1 = *(const float4*)(mrp + 4);
    float4 b0 = *(const float4*)mip, b1 = *(const float4*)(mip + 4);
    float mr[8] = {a0.x, a0.y, a0.z, a0.w, a1.x, a1.y, a1.z, a1.w};
    float mi[8] = {b0.x, b0.y, b0.z, b0.w, b1.x, b1.y, b1.z, b1.w};
    // sim
    float sp = 0.f;
    #pragma unroll
    for (int x = 0; x < 8; ++x) sp += mr[x] * s_zr[r][d0 + x] + mi[x] * s_zi[r][d0 + x];
    sp += __shfl_xor(sp, 1); sp += __shfl_xor(sp, 2); sp += __shfl_xor(sp, 4);
    if (k == 0) s_sim[s] = sp;
    __syncthreads();
    if (t < 32) {
      float v = s_sim[t];
      float mx = v;
      #pragma unroll
      for (int m = 16; m >= 1; m >>= 1) mx = fmaxf(mx, __shfl_xor(mx, m));
      float e = expf(v - mx);
      float smm = e;
      #pragma unroll
      for (int m = 16; m >= 1; m >>= 1) smm += __shfl_xor(smm, m);
      s_attn[t] = e / smm;
    }
    __syncthreads();
    const float aw = s_attn[s];
    // read_r / read_i: reduce att*mem over slots
    float pr[8], pi[8];
    #pragma unroll
    for (int x = 0; x < 8; ++x) { pr[x] = aw * mr[x]; pi[x] = aw * mi[x]; }
    #pragma unroll
    for (int m = 8; m <= 32; m <<= 1) {
      #pragma unroll
      for (int x = 0; x < 8; ++x) { pr[x] += __shfl_xor(pr[x], m); pi[x] += __shfl_xor(pi[x], m); }
    }
    if (lane < 8) {
      #pragma unroll
      for (int x = 0; x < 8; ++x) { s_rr[wv][lane][x] = pr[x]; s_ri[wv][lane][x] = pi[x]; }
    }
    __syncthreads();
    if (t < 64) {
      const int kk = t >> 3, xx = t & 7;
      float rv = s_rr[0][kk][xx] + s_rr[1][kk][xx] + s_rr[2][kk][xx] + s_rr[3][kk][xx];
      float iv = s_ri[0][kk][xx] + s_ri[1][kk][xx] + s_ri[2][kk][xx] + s_ri[3][kk][xx];
      float* orow = P.out + bb * RSTRIDE;
      orow[256 + t] = rv;
      orow[320 + t] = iv;
    }
    // nm = layernorm(tanh(mem + eff*(curr - mem)))
    const float eff = s_eff[r][s];
    float nr[8], ni[8];
    #pragma unroll
    for (int x = 0; x < 8; ++x) {
      nr[x] = tanhf(mr[x] + eff * (s_zr[r][d0 + x] - mr[x]));
      ni[x] = tanhf(mi[x] + eff * (s_zi[r][d0 + x] - mi[x]));
    }
    float sR = 0.f, sI = 0.f;
    #pragma unroll
    for (int x = 0; x < 8; ++x) { sR += nr[x]; sI += ni[x]; }
    sR += __shfl_xor(sR, 1); sR += __shfl_xor(sR, 2); sR += __shfl_xor(sR, 4);
    sI += __shfl_xor(sI, 1); sI += __shfl_xor(sI, 2); sI += __shfl_xor(sI, 4);
    const float mR = sR * (1.f / 64.f), mI = sI * (1.f / 64.f);
    float vR = 0.f, vI = 0.f;
    #pragma unroll
    for (int x = 0; x < 8; ++x) {
      float dr = nr[x] - mR; vR += dr * dr;
      float di = ni[x] - mI; vI += di * di;
    }
    vR += __shfl_xor(vR, 1); vR += __shfl_xor(vR, 2); vR += __shfl_xor(vR, 4);
    vI += __shfl_xor(vI, 1); vI += __shfl_xor(vI, 2); vI += __shfl_xor(vI, 4);
    const float invR = 1.f / sqrtf(vR * (1.f / 64.f) + 1e-6f);
    const float invI = 1.f / sqrtf(vI * (1.f / 64.f) + 1e-6f);
    float outR[8], outI[8];
    #pragma unroll
    for (int x = 0; x < 8; ++x) {
      const int d = d0 + x;
      outR[x] = (nr[x] - mR) * invR * P.ln_gr[d] + P.ln_br[d];
      outI[x] = (ni[x] - mI) * invI * P.ln_gi[d] + P.ln_bi[d];
    }
    float* orow = P.out + bb * RSTRIDE;
    *(float4*)&orow[640 + s * 64 + d0]      = make_float4(outR[0], outR[1], outR[2], outR[3]);
    *(float4*)&orow[640 + s * 64 + d0 + 4]  = make_float4(outR[4], outR[5], outR[6], outR[7]);
    *(float4*)&orow[2688 + s * 64 + d0]     = make_float4(outI[0], outI[1], outI[2], outI[3]);
    *(float4*)&orow[2688 + s * 64 + d0 + 4] = make_float4(outI[4], outI[5], outI[6], outI[7]);
    __syncthreads();
  }

  // ---------------- P5: palette attends (vis/aud) -> exp_r/exp_i ----------------
  {
    const int r = t >> 5, a = t & 31;
    float sc = 0.f;
    for (int jj = 0; jj < 128; jj += 4) {
      const float4 sf = *(const float4*)&s_sf[r][jj];
      const float4 pv = *(const float4*)&P.vis_pal[a * 128 + jj];
      sc += sf.x * pv.x + sf.y * pv.y + sf.z * pv.z + sf.w * pv.w;
    }
    float mx = sc;
    #pragma unroll
    for (int m = 16; m >= 1; m >>= 1) mx = fmaxf(mx, __shfl_xor(mx, m));
    float e = expf(sc - mx);
    float sm = e;
    #pragma unroll
    for (int m = 16; m >= 1; m >>= 1) sm += __shfl_xor(sm, m);
    u.pal.palp[r][a] = e / sm;
  }
  __syncthreads();
  {
    const int j = t & 127, rp = t >> 7;
    float acc[4] = {0.f, 0.f, 0.f, 0.f};
    for (int a = 0; a < 32; ++a) {
      const float pv = P.vis_pal[a * 128 + j];
      #pragma unroll
      for (int q = 0; q < 4; ++q) acc[q] += u.pal.palp[rp + q * 2][a] * pv;
    }
    #pragma unroll
    for (int q = 0; q < 4; ++q) u.pal.vis[rp + q * 2][j] = acc[q];
  }
  __syncthreads();
  {
    const int r = t >> 5, a = t & 31;
    float sc = 0.f;
    for (int jj = 0; jj < 128; jj += 4) {
      const float4 sf = *(const float4*)&s_sf[r][jj];
      const float4 pv = *(const float4*)&P.aud_pal[a * 128 + jj];
      sc += sf.x * pv.x + sf.y * pv.y + sf.z * pv.z + sf.w * pv.w;
    }
    float mx = sc;
    #pragma unroll
    for (int m = 16; m >= 1; m >>= 1) mx = fmaxf(mx, __shfl_xor(mx, m));
    float e = expf(sc - mx);
    float sm = e;
    #pragma unroll
    for (int m = 16; m >= 1; m >>= 1) sm += __shfl_xor(sm, m);
    u.pal.palp[r][a] = e / sm;   // vis[] field untouched; only palp reused
  }
  __syncthreads();
  {
    const int j = t & 127, rp = t >> 7;
    float acc[4] = {0.f, 0.f, 0.f, 0.f};
    for (int a = 0; a < 32; ++a) {
      const float pv = P.aud_pal[a * 128 + j];
      #pragma unroll
      for (int q = 0; q < 4; ++q) acc[q] += u.pal.palp[rp + q * 2][a] * pv;
    }
    #pragma unroll
    for (int q = 0; q < 4; ++q) {
      const int rr = rp + q * 2;
      const size_t bb = (size_t)bid * NROWS + rr;
      float* orow = P.out + bb * RSTRIDE;
      if (j < 64) orow[448 + j] = u.pal.vis[rr][64 + j] + acc[q];        // exp_i
      else        orow[384 + (j - 64)] = u.pal.vis[rr][j - 64] - acc[q]; // exp_r
    }
  }

  // ---------------- P6: vq_r/vq_i, g_r/g_i, scalars ----------------
  {
    const int j = t & 63, g = t >> 6;
    #pragma unroll 1
    for (int r = 0; r < NROWS; ++r) {
      const size_t bb = (size_t)bid * NROWS + r;
      float* orow = P.out + bb * RSTRIDE;
      if (g == 0) {
        float z = s_zr[r][j];
        float cv = P.codebook[(size_t)s_idx[r] * 128 + j];
        orow[j] = z + (cv - z);        // straight-through
      } else if (g == 1) {
        float z = s_zi[r][j];
        float cv = P.codebook[(size_t)s_idx[r] * 128 + 64 + j];
        orow[64 + j] = z + (cv - z);
      } else if (g == 2) {
        orow[128 + j] = s_vr[r][j] * s_gate[r];
      } else {
        orow[192 + j] = s_vi[r][j] * s_gate[r];
      }
    }
  }
  if (t < NROWS) {
    P.out[OFF_VQLOSS + (size_t)bid * NROWS + t] = s_vqls[t];
    P.out[OFF_IDX + (size_t)bid * NROWS + t] = (float)s_idx[t];
  }
  if (t == 0) {
    float es = 0.f;
    #pragma unroll
    for (int r = 0; r < NROWS; ++r) es += s_rowent[r];
    P.slot_part[bid] = es;
  }
}

__global__ __launch_bounds__(256) void finalize_k(const int* hist, const float* slot_part,
                                                  float* out) {
  const int t = threadIdx.x;
  __shared__ float red[256];
  float se = 0.f;
  for (int i = t; i < NBLOCKS; i += 256) se += slot_part[i];
  red[t] = se;
  __syncthreads();
  for (int off = 128; off >= 1; off >>= 1) {
    if (t < off) red[t] += red[t + off];
    __syncthreads();
  }
  if (t == 0) out[OFF_SENT] = red[0] / 8192.0f;
  __syncthreads();
  float ne = 0.f;
  if (t < 128) {
    float pp = (float)hist[t] / 8192.0f;
    ne = -(pp * logf(pp + 1e-10f));
  }
  red[t] = ne;
  __syncthreads();
  for (int off = 128; off >= 1; off >>= 1) {
    if (t < off) red[t] += red[t + off];
    __syncthreads();
  }
  if (t == 0) out[OFF_NENT] = red[0] / logf(128.0f);
}

extern "C" void kernel_launch(void* const* d_in, const int* in_sizes, int n_in,
                              void* d_out, int out_size, void* d_ws, size_t ws_size,
                              hipStream_t stream) {
  (void)in_sizes; (void)n_in; (void)out_size; (void)ws_size;
  Params P;
  P.curr_r   = (const float*)d_in[0];
  P.curr_i   = (const float*)d_in[1];
  P.mem_r    = (const float*)d_in[2];
  P.mem_i    = (const float*)d_in[3];
  P.codebook = (const float*)d_in[4];
  P.qkv_Wr   = (const float*)d_in[5];
  P.qkv_Wi   = (const float*)d_in[6];
  P.qkv_br   = (const float*)d_in[7];
  P.qkv_bi   = (const float*)d_in[8];
  P.quad_Wr  = (const float*)d_in[9];
  P.quad_Wi  = (const float*)d_in[10];
  P.quad_br  = (const float*)d_in[11];
  P.quad_bi  = (const float*)d_in[12];
  P.sens_Wr  = (const float*)d_in[13];
  P.sens_Wi  = (const float*)d_in[14];
  P.sens_br  = (const float*)d_in[15];
  P.sens_bi  = (const float*)d_in[16];
  P.vis_pal  = (const float*)d_in[17];
  P.aud_pal  = (const float*)d_in[18];
  P.gate_W   = (const float*)d_in[19];
  P.gate_b   = (const float*)d_in[20];
  P.addr_W   = (const float*)d_in[21];
  P.addr_b   = (const float*)d_in[22];
  P.ln_gr    = (const float*)d_in[23];
  P.ln_br    = (const float*)d_in[24];
  P.ln_gi    = (const float*)d_in[25];
  P.ln_bi    = (const float*)d_in[26];
  P.out = (float*)d_out;
  P.hist = (int*)d_ws;
  P.slot_part = (float*)((char*)d_ws + 512);

  hipMemsetAsync(d_ws, 0, 512, stream);
  fused_main<<<dim3(NBLOCKS), dim3(256), 0, stream>>>(P);
  finalize_k<<<dim3(1), dim3(256), 0, stream>>>(P.hist, P.slot_part, (float*)d_out);
}

// Round 8
// 287.347 us; speedup vs baseline: 2.5594x; 1.3373x over previous
//
#include <hip/hip_runtime.h>
#include <hip/hip_bf16.h>

// SACRSN_v84 — v8: two-kernel split.
//   fused_main (1024 blk): VQ, complex linears, gate, palettes, vq/g/q/exp writes.
//   mem_kernel (8192 blk): per-row addr-softmax/top3/eff + mem attention + tanh/LN
//                          (95% of HBM traffic, streaming, high occupancy).

#define NROWS 8
#define NBLOCKS 1024
#define RSTRIDE 4736

static constexpr size_t OFF_VQLOSS = 38797312UL;  // 8192*4736
static constexpr size_t OFF_IDX    = 38805504UL;
static constexpr size_t OFF_SENT   = 38813696UL;
static constexpr size_t OFF_NENT   = 38813697UL;

struct Params {
  const float* curr_r; const float* curr_i;
  const float* mem_r;  const float* mem_i;
  const float* codebook;
  const float* qkv_Wr; const float* qkv_Wi; const float* qkv_br; const float* qkv_bi;
  const float* quad_Wr; const float* quad_Wi; const float* quad_br; const float* quad_bi;
  const float* sens_Wr; const float* sens_Wi; const float* sens_br; const float* sens_bi;
  const float* vis_pal; const float* aud_pal;
  const float* gate_W; const float* gate_b;
  const float* addr_W; const float* addr_b;
  const float* ln_gr; const float* ln_br; const float* ln_gi; const float* ln_bi;
  float* out;
  int* hist;          // ws: 128 ints
  float* rowent;      // ws + 512 B: 8192 floats
};

union __align__(16) ScratchU {
  struct { double cbn[128]; double redd[256]; } vq;               // 3 KB
  float w[64][64];                                                // 16 KB staged weights
  struct { float vis[NROWS][128]; float palp[NROWS][32]; } pal;   // 5 KB
};

// ================= kernel A: per-row dense math (no mem_r/mem_i) =================
__global__ __launch_bounds__(256) void fused_main(Params P) {
  const int t = threadIdx.x;
  const int bid = blockIdx.x;
  const int lane = t & 63;
  const int wv = t >> 6;

  __shared__ __align__(16) float s_zr[NROWS][64], s_zi[NROWS][64];
  __shared__ ScratchU u;
  __shared__ float s_qr[NROWS][64], s_qi[NROWS][64];
  __shared__ float s_kr[NROWS][64], s_ki[NROWS][64];
  __shared__ float s_vr[NROWS][64], s_vi[NROWS][64];
  __shared__ __align__(16) float s_sf[NROWS][128];
  __shared__ float s_gate[NROWS], s_vqls[NROWS];
  __shared__ int s_idx[NROWS];
  __shared__ double s_cv[2];
  __shared__ int s_ci[2];

  // ---- P0: stage curr (z) ----
  {
    const float* cr = P.curr_r + (size_t)bid * (NROWS * 64);
    const float* ci = P.curr_i + (size_t)bid * (NROWS * 64);
    float* zr = &s_zr[0][0];
    float* zi = &s_zi[0][0];
    for (int i = t; i < NROWS * 64; i += 256) { zr[i] = cr[i]; zi[i] = ci[i]; }
  }

  // ---- P0b: codebook squared norms (f64) ----
  {
    const int c = t & 127, h = t >> 7;
    const float* cb = P.codebook + c * 128 + h * 64;
    double a = 0.0;
    for (int d = 0; d < 64; ++d) { double w = (double)cb[d]; a = fma(w, w, a); }
    u.vq.redd[t] = a;
    __syncthreads();
    if (t < 128) u.vq.cbn[t] = u.vq.redd[t] + u.vq.redd[t + 128];
    __syncthreads();
  }

  // ---- P1: VQ argmin (f64, first-index tie-break) ----
  {
    const int c = t & 127, h = t >> 7;
    const float* cb = P.codebook + c * 128 + h * 64;
    const float (*zb)[64] = h ? s_zi : s_zr;
    double acc[NROWS];
    #pragma unroll
    for (int r = 0; r < NROWS; ++r) acc[r] = 0.0;
    for (int d = 0; d < 64; ++d) {
      const double w = (double)cb[d];
      #pragma unroll
      for (int r = 0; r < NROWS; ++r) acc[r] = fma(w, (double)zb[r][d], acc[r]);
    }
    #pragma unroll 1
    for (int r = 0; r < NROWS; ++r) {
      u.vq.redd[t] = acc[r];
      __syncthreads();
      if (t < 128) {
        double sv = u.vq.cbn[t] - 2.0 * (u.vq.redd[t] + u.vq.redd[t + 128]);
        int si = t;
        #pragma unroll
        for (int m = 1; m <= 32; m <<= 1) {
          double ov = __shfl_xor(sv, m);
          int oi = __shfl_xor(si, m);
          if (ov < sv || (ov == sv && oi < si)) { sv = ov; si = oi; }
        }
        if (lane == 0) { s_cv[t >> 6] = sv; s_ci[t >> 6] = si; }
      }
      __syncthreads();
      if (t == 0) {
        int win = (s_cv[1] < s_cv[0] || (s_cv[1] == s_cv[0] && s_ci[1] < s_ci[0]))
                  ? s_ci[1] : s_ci[0];
        s_idx[r] = win;
        atomicAdd(&P.hist[win], 1);
      }
      __syncthreads();
    }
  }

  // ---- P1b: vq_loss ----
  {
    #pragma unroll
    for (int rr = 0; rr < 2; ++rr) {
      const int r = wv * 2 + rr;
      const float* cb = P.codebook + (size_t)s_idx[r] * 128;
      float d0_ = cb[lane] - s_zr[r][lane];
      float d1_ = cb[64 + lane] - s_zi[r][lane];
      float v = d0_ * d0_ + d1_ * d1_;
      #pragma unroll
      for (int m = 1; m <= 32; m <<= 1) v += __shfl_xor(v, m);
      if (lane == 0) s_vqls[r] = 0.25f * v * (1.0f / 128.0f);
    }
  }

  // ---- P2: five complex linears ----
  {
    const int j = t & 63, rg = t >> 6;
    const float* Wr_tab[5] = {P.qkv_Wr, P.qkv_Wr + 4096, P.qkv_Wr + 8192, P.quad_Wr, P.sens_Wr};
    const float* Wi_tab[5] = {P.qkv_Wi, P.qkv_Wi + 4096, P.qkv_Wi + 8192, P.quad_Wi, P.sens_Wi};
    const float* br_tab[5] = {P.qkv_br, P.qkv_br + 64, P.qkv_br + 128, P.quad_br, P.sens_br};
    const float* bi_tab[5] = {P.qkv_bi, P.qkv_bi + 64, P.qkv_bi + 128, P.quad_bi, P.sens_bi};
    #pragma unroll 1
    for (int cl = 0; cl < 5; ++cl) {
      __syncthreads();
      { const float4* src = (const float4*)Wr_tab[cl];
        float4* dst = (float4*)&u.w[0][0];
        for (int i = t; i < 1024; i += 256) dst[i] = src[i]; }
      __syncthreads();
      float aRR0 = 0.f, aRR1 = 0.f, aIR0 = 0.f, aIR1 = 0.f;
      for (int d4 = 0; d4 < 64; d4 += 4) {
        float4 zr0 = *(const float4*)&s_zr[rg][d4];
        float4 zr1 = *(const float4*)&s_zr[rg + 4][d4];
        float4 zi0 = *(const float4*)&s_zi[rg][d4];
        float4 zi1 = *(const float4*)&s_zi[rg + 4][d4];
        float w0 = u.w[d4 + 0][j], w1 = u.w[d4 + 1][j];
        float w2 = u.w[d4 + 2][j], w3 = u.w[d4 + 3][j];
        aRR0 += zr0.x * w0 + zr0.y * w1 + zr0.z * w2 + zr0.w * w3;
        aRR1 += zr1.x * w0 + zr1.y * w1 + zr1.z * w2 + zr1.w * w3;
        aIR0 += zi0.x * w0 + zi0.y * w1 + zi0.z * w2 + zi0.w * w3;
        aIR1 += zi1.x * w0 + zi1.y * w1 + zi1.z * w2 + zi1.w * w3;
      }
      __syncthreads();
      { const float4* src = (const float4*)Wi_tab[cl];
        float4* dst = (float4*)&u.w[0][0];
        for (int i = t; i < 1024; i += 256) dst[i] = src[i]; }
      __syncthreads();
      float aRI0 = 0.f, aRI1 = 0.f, aII0 = 0.f, aII1 = 0.f;
      for (int d4 = 0; d4 < 64; d4 += 4) {
        float4 zr0 = *(const float4*)&s_zr[rg][d4];
        float4 zr1 = *(const float4*)&s_zr[rg + 4][d4];
        float4 zi0 = *(const float4*)&s_zi[rg][d4];
        float4 zi1 = *(const float4*)&s_zi[rg + 4][d4];
        float w0 = u.w[d4 + 0][j], w1 = u.w[d4 + 1][j];
        float w2 = u.w[d4 + 2][j], w3 = u.w[d4 + 3][j];
        aRI0 += zr0.x * w0 + zr0.y * w1 + zr0.z * w2 + zr0.w * w3;
        aRI1 += zr1.x * w0 + zr1.y * w1 + zr1.z * w2 + zr1.w * w3;
        aII0 += zi0.x * w0 + zi0.y * w1 + zi0.z * w2 + zi0.w * w3;
        aII1 += zi1.x * w0 + zi1.y * w1 + zi1.z * w2 + zi1.w * w3;
      }
      const float brj = br_tab[cl][j], bij = bi_tab[cl][j];
      #pragma unroll
      for (int hh = 0; hh < 2; ++hh) {
        const int r = rg + hh * 4;
        const float pRR = hh ? aRR1 : aRR0;
        const float pII = hh ? aII1 : aII0;
        const float pRI = hh ? aRI1 : aRI0;
        const float pIR = hh ? aIR1 : aIR0;
        const float oR = (pRR + brj) - (pII + bij);
        const float oI = (pRI + bij) + (pIR + brj);
        if (cl == 0)      { s_qr[r][j] = oR; s_qi[r][j] = oI; }
        else if (cl == 1) { s_kr[r][j] = oR; s_ki[r][j] = oI; }
        else if (cl == 2) { s_vr[r][j] = oR; s_vi[r][j] = oI; }
        else if (cl == 3) {
          float* orow = P.out + ((size_t)bid * NROWS + r) * RSTRIDE;
          orow[512 + j] = -oI;
          orow[576 + j] = oR;
        } else            { s_sf[r][j] = oR; s_sf[r][64 + j] = oI; }
      }
    }
    __syncthreads();
  }

  // ---- P3: gate only ----
  {
    const int r = t >> 5, l = t & 31;
    float g = s_qr[r][l] * s_kr[r][l] + s_qi[r][l] * s_ki[r][l]
            + s_qr[r][l + 32] * s_kr[r][l + 32] + s_qi[r][l + 32] * s_ki[r][l + 32];
    #pragma unroll
    for (int m = 16; m >= 1; m >>= 1) g += __shfl_xor(g, m);
    if (l == 0) s_gate[r] = 1.f / (1.f + expf(-g));
  }
  __syncthreads();

  // ---- P5: palette attends ----
  {
    const int r = t >> 5, a = t & 31;
    float sc = 0.f;
    for (int jj = 0; jj < 128; jj += 4) {
      const float4 sf = *(const float4*)&s_sf[r][jj];
      const float4 pv = *(const float4*)&P.vis_pal[a * 128 + jj];
      sc += sf.x * pv.x + sf.y * pv.y + sf.z * pv.z + sf.w * pv.w;
    }
    float mx = sc;
    #pragma unroll
    for (int m = 16; m >= 1; m >>= 1) mx = fmaxf(mx, __shfl_xor(mx, m));
    float e = expf(sc - mx);
    float sm = e;
    #pragma unroll
    for (int m = 16; m >= 1; m >>= 1) sm += __shfl_xor(sm, m);
    u.pal.palp[r][a] = e / sm;
  }
  __syncthreads();
  {
    const int j = t & 127, rp = t >> 7;
    float acc[4] = {0.f, 0.f, 0.f, 0.f};
    for (int a = 0; a < 32; ++a) {
      const float pv = P.vis_pal[a * 128 + j];
      #pragma unroll
      for (int q = 0; q < 4; ++q) acc[q] += u.pal.palp[rp + q * 2][a] * pv;
    }
    #pragma unroll
    for (int q = 0; q < 4; ++q) u.pal.vis[rp + q * 2][j] = acc[q];
  }
  __syncthreads();
  {
    const int r = t >> 5, a = t & 31;
    float sc = 0.f;
    for (int jj = 0; jj < 128; jj += 4) {
      const float4 sf = *(const float4*)&s_sf[r][jj];
      const float4 pv = *(const float4*)&P.aud_pal[a * 128 + jj];
      sc += sf.x * pv.x + sf.y * pv.y + sf.z * pv.z + sf.w * pv.w;
    }
    float mx = sc;
    #pragma unroll
    for (int m = 16; m >= 1; m >>= 1) mx = fmaxf(mx, __shfl_xor(mx, m));
    float e = expf(sc - mx);
    float sm = e;
    #pragma unroll
    for (int m = 16; m >= 1; m >>= 1) sm += __shfl_xor(sm, m);
    u.pal.palp[r][a] = e / sm;
  }
  __syncthreads();
  {
    const int j = t & 127, rp = t >> 7;
    float acc[4] = {0.f, 0.f, 0.f, 0.f};
    for (int a = 0; a < 32; ++a) {
      const float pv = P.aud_pal[a * 128 + j];
      #pragma unroll
      for (int q = 0; q < 4; ++q) acc[q] += u.pal.palp[rp + q * 2][a] * pv;
    }
    #pragma unroll
    for (int q = 0; q < 4; ++q) {
      const int rr = rp + q * 2;
      const size_t bb = (size_t)bid * NROWS + rr;
      float* orow = P.out + bb * RSTRIDE;
      if (j < 64) orow[448 + j] = u.pal.vis[rr][64 + j] + acc[q];        // exp_i
      else        orow[384 + (j - 64)] = u.pal.vis[rr][j - 64] - acc[q]; // exp_r
    }
  }

  // ---- P6: vq_r/vq_i, g_r/g_i, scalars ----
  {
    const int j = t & 63, g = t >> 6;
    #pragma unroll 1
    for (int r = 0; r < NROWS; ++r) {
      const size_t bb = (size_t)bid * NROWS + r;
      float* orow = P.out + bb * RSTRIDE;
      if (g == 0) {
        float z = s_zr[r][j];
        float cv = P.codebook[(size_t)s_idx[r] * 128 + j];
        orow[j] = z + (cv - z);
      } else if (g == 1) {
        float z = s_zi[r][j];
        float cv = P.codebook[(size_t)s_idx[r] * 128 + 64 + j];
        orow[64 + j] = z + (cv - z);
      } else if (g == 2) {
        orow[128 + j] = s_vr[r][j] * s_gate[r];
      } else {
        orow[192 + j] = s_vi[r][j] * s_gate[r];
      }
    }
  }
  if (t < NROWS) {
    P.out[OFF_VQLOSS + (size_t)bid * NROWS + t] = s_vqls[t];
    P.out[OFF_IDX + (size_t)bid * NROWS + t] = (float)s_idx[t];
  }
}

// ================= kernel B: per-row memory attention + tanh/LN (streaming) =================
__global__ __launch_bounds__(256, 4) void mem_kernel(Params P) {
  const int b = blockIdx.x;       // row 0..8191
  const int t = threadIdx.x;
  const int lane = t & 63;
  const int wv = t >> 6;

  __shared__ float zr[64], zi[64];
  __shared__ float lp[4][32];
  __shared__ float s_eff[32];
  __shared__ float s_sim[32], s_attn[32];
  __shared__ float s_rr[4][8][8], s_ri[4][8][8];
  __shared__ float s_wg;

  // phase 1: stage z
  if (t < 64)       zr[t]      = P.curr_r[(size_t)b * 64 + t];
  else if (t < 128) zi[t - 64] = P.curr_i[(size_t)b * 64 + (t - 64)];
  __syncthreads();

  // phase 2: mem loads + sim partials; addr-logit partials; write_gate partial
  const size_t bb = (size_t)b;
  const int s = t >> 3, k = t & 7, d0 = k * 8;
  const float* mrp = P.mem_r + ((bb * 32 + s) * 64 + d0);
  const float* mip = P.mem_i + ((bb * 32 + s) * 64 + d0);
  float4 a0 = *(const float4*)mrp, a1 = *(const float4*)(mrp + 4);
  float4 b0 = *(const float4*)mip, b1 = *(const float4*)(mip + 4);
  float mr[8] = {a0.x, a0.y, a0.z, a0.w, a1.x, a1.y, a1.z, a1.w};
  float mi[8] = {b0.x, b0.y, b0.z, b0.w, b1.x, b1.y, b1.z, b1.w};

  if (t < 128) {
    const int q = t >> 5, l = t & 31;
    const float* zz = (q < 2) ? zr : zi;
    const int zb = (q & 1) * 32;
    float a = 0.f;
    for (int i = 0; i < 32; ++i) a += zz[zb + i] * P.addr_W[(q * 32 + i) * 32 + l];
    lp[q][l] = a;
  } else if (t < 192) {
    const int j = t - 128;          // 0..63, wave 2
    float tw = zr[j] * P.gate_W[j] + zi[j] * P.gate_W[64 + j];
    #pragma unroll
    for (int m = 1; m <= 32; m <<= 1) tw += __shfl_xor(tw, m);
    if (j == 0) s_wg = tw;
  }

  float sp = 0.f;
  #pragma unroll
  for (int x = 0; x < 8; ++x) sp += mr[x] * zr[d0 + x] + mi[x] * zi[d0 + x];
  sp += __shfl_xor(sp, 1); sp += __shfl_xor(sp, 2); sp += __shfl_xor(sp, 4);
  if (k == 0) s_sim[s] = sp;
  __syncthreads();

  // phase 3: wave 0 -> sim softmax; wave 1 lanes 0..31 -> addr softmax/top3/eff
  if (t < 32) {
    float v = s_sim[t];
    float mx = v;
    #pragma unroll
    for (int m = 16; m >= 1; m >>= 1) mx = fmaxf(mx, __shfl_xor(mx, m));
    float e = expf(v - mx);
    float sm = e;
    #pragma unroll
    for (int m = 16; m >= 1; m >>= 1) sm += __shfl_xor(sm, m);
    s_attn[t] = e / sm;
  } else if (t >= 64 && t < 96) {
    const int l = t - 64;
    float lg = lp[0][l] + lp[1][l] + lp[2][l] + lp[3][l] + P.addr_b[l];
    float mx = lg;
    #pragma unroll
    for (int m = 16; m >= 1; m >>= 1) mx = fmaxf(mx, __shfl_xor(mx, m));
    float e = expf(lg - mx);
    float sm = e;
    #pragma unroll
    for (int m = 16; m >= 1; m >>= 1) sm += __shfl_xor(sm, m);
    const float w = e / sm;
    float es = -(w * logf(w + 1e-10f));
    #pragma unroll
    for (int m = 16; m >= 1; m >>= 1) es += __shfl_xor(es, m);
    if (l == 0) P.rowent[b] = es;
    // top-3 (lax.top_k: ties -> lower index)
    const float myw = w;
    bool picked = false;
    float val = w; int idx = l;
    float sumtop = 0.f;
    #pragma unroll
    for (int it = 0; it < 3; ++it) {
      float v2 = val; int i2 = idx;
      #pragma unroll
      for (int m = 16; m >= 1; m >>= 1) {
        float ov = __shfl_xor(v2, m); int oi = __shfl_xor(i2, m);
        if (ov > v2 || (ov == v2 && oi < i2)) { v2 = ov; i2 = oi; }
      }
      sumtop += v2;
      if (l == i2) { picked = true; val = -1e30f; }
    }
    const float wgate = 1.f / (1.f + expf(-(s_wg + P.gate_b[0])));
    s_eff[l] = picked ? wgate * (myw / (sumtop + 1e-6f)) : 0.f;
  }
  __syncthreads();

  // phase 4: read reduction + tanh/LN + stores
  const float aw = s_attn[s];
  {
    float pr[8], pi[8];
    #pragma unroll
    for (int x = 0; x < 8; ++x) { pr[x] = aw * mr[x]; pi[x] = aw * mi[x]; }
    #pragma unroll
    for (int m = 8; m <= 32; m <<= 1) {
      #pragma unroll
      for (int x = 0; x < 8; ++x) { pr[x] += __shfl_xor(pr[x], m); pi[x] += __shfl_xor(pi[x], m); }
    }
    if (lane < 8) {
      #pragma unroll
      for (int x = 0; x < 8; ++x) { s_rr[wv][lane][x] = pr[x]; s_ri[wv][lane][x] = pi[x]; }
    }
  }
  // nm = layernorm(tanh(mem + eff*(curr - mem)))
  {
    const float eff = s_eff[s];
    float nr[8], ni[8];
    #pragma unroll
    for (int x = 0; x < 8; ++x) {
      nr[x] = tanhf(mr[x] + eff * (zr[d0 + x] - mr[x]));
      ni[x] = tanhf(mi[x] + eff * (zi[d0 + x] - mi[x]));
    }
    float sR = 0.f, sI = 0.f;
    #pragma unroll
    for (int x = 0; x < 8; ++x) { sR += nr[x]; sI += ni[x]; }
    sR += __shfl_xor(sR, 1); sR += __shfl_xor(sR, 2); sR += __shfl_xor(sR, 4);
    sI += __shfl_xor(sI, 1); sI += __shfl_xor(sI, 2); sI += __shfl_xor(sI, 4);
    const float mR = sR * (1.f / 64.f), mI = sI * (1.f / 64.f);
    float vR = 0.f, vI = 0.f;
    #pragma unroll
    for (int x = 0; x < 8; ++x) {
      float dr = nr[x] - mR; vR += dr * dr;
      float di = ni[x] - mI; vI += di * di;
    }
    vR += __shfl_xor(vR, 1); vR += __shfl_xor(vR, 2); vR += __shfl_xor(vR, 4);
    vI += __shfl_xor(vI, 1); vI += __shfl_xor(vI, 2); vI += __shfl_xor(vI, 4);
    const float invR = 1.f / sqrtf(vR * (1.f / 64.f) + 1e-6f);
    const float invI = 1.f / sqrtf(vI * (1.f / 64.f) + 1e-6f);
    float* orow = P.out + bb * RSTRIDE;
    float oR[8], oI[8];
    #pragma unroll
    for (int x = 0; x < 8; ++x) {
      const int d = d0 + x;
      oR[x] = (nr[x] - mR) * invR * P.ln_gr[d] + P.ln_br[d];
      oI[x] = (ni[x] - mI) * invI * P.ln_gi[d] + P.ln_bi[d];
    }
    *(float4*)&orow[640 + s * 64 + d0]      = make_float4(oR[0], oR[1], oR[2], oR[3]);
    *(float4*)&orow[640 + s * 64 + d0 + 4]  = make_float4(oR[4], oR[5], oR[6], oR[7]);
    *(float4*)&orow[2688 + s * 64 + d0]     = make_float4(oI[0], oI[1], oI[2], oI[3]);
    *(float4*)&orow[2688 + s * 64 + d0 + 4] = make_float4(oI[4], oI[5], oI[6], oI[7]);
  }
  __syncthreads();
  if (t < 64) {
    const int kk = t >> 3, xx = t & 7;
    float rv = s_rr[0][kk][xx] + s_rr[1][kk][xx] + s_rr[2][kk][xx] + s_rr[3][kk][xx];
    float iv = s_ri[0][kk][xx] + s_ri[1][kk][xx] + s_ri[2][kk][xx] + s_ri[3][kk][xx];
    float* orow = P.out + bb * RSTRIDE;
    orow[256 + t] = rv;
    orow[320 + t] = iv;
  }
}

__global__ __launch_bounds__(256) void finalize_k(const int* hist, const float* rowent,
                                                  float* out) {
  const int t = threadIdx.x;
  __shared__ float red[256];
  float se = 0.f;
  for (int i = t; i < 8192; i += 256) se += rowent[i];
  red[t] = se;
  __syncthreads();
  for (int off = 128; off >= 1; off >>= 1) {
    if (t < off) red[t] += red[t + off];
    __syncthreads();
  }
  if (t == 0) out[OFF_SENT] = red[0] / 8192.0f;
  __syncthreads();
  float ne = 0.f;
  if (t < 128) {
    const float pp = (float)hist[t] / 8192.0f;
    ne = -(pp * logf(pp + 1e-10f));
  }
  red[t] = ne;
  __syncthreads();
  for (int off = 128; off >= 1; off >>= 1) {
    if (t < off) red[t] += red[t + off];
    __syncthreads();
  }
  if (t == 0) out[OFF_NENT] = red[0] / logf(128.0f);
}

extern "C" void kernel_launch(void* const* d_in, const int* in_sizes, int n_in,
                              void* d_out, int out_size, void* d_ws, size_t ws_size,
                              hipStream_t stream) {
  (void)in_sizes; (void)n_in; (void)out_size; (void)ws_size;
  Params P;
  P.curr_r   = (const float*)d_in[0];
  P.curr_i   = (const float*)d_in[1];
  P.mem_r    = (const float*)d_in[2];
  P.mem_i    = (const float*)d_in[3];
  P.codebook = (const float*)d_in[4];
  P.qkv_Wr   = (const float*)d_in[5];
  P.qkv_Wi   = (const float*)d_in[6];
  P.qkv_br   = (const float*)d_in[7];
  P.qkv_bi   = (const float*)d_in[8];
  P.quad_Wr  = (const float*)d_in[9];
  P.quad_Wi  = (const float*)d_in[10];
  P.quad_br  = (const float*)d_in[11];
  P.quad_bi  = (const float*)d_in[12];
  P.sens_Wr  = (const float*)d_in[13];
  P.sens_Wi  = (const float*)d_in[14];
  P.sens_br  = (const float*)d_in[15];
  P.sens_bi  = (const float*)d_in[16];
  P.vis_pal  = (const float*)d_in[17];
  P.aud_pal  = (const float*)d_in[18];
  P.gate_W   = (const float*)d_in[19];
  P.gate_b   = (const float*)d_in[20];
  P.addr_W   = (const float*)d_in[21];
  P.addr_b   = (const float*)d_in[22];
  P.ln_gr    = (const float*)d_in[23];
  P.ln_br    = (const float*)d_in[24];
  P.ln_gi    = (const float*)d_in[25];
  P.ln_bi    = (const float*)d_in[26];
  P.out = (float*)d_out;
  P.hist = (int*)d_ws;
  P.rowent = (float*)((char*)d_ws + 512);

  hipMemsetAsync(d_ws, 0, 512, stream);
  mem_kernel<<<dim3(8192), dim3(256), 0, stream>>>(P);
  fused_main<<<dim3(NBLOCKS), dim3(256), 0, stream>>>(P);
  finalize_k<<<dim3(1), dim3(256), 0, stream>>>(P.hist, P.rowent, (float*)d_out);
}